// Round 1
// baseline (194.866 us; speedup 1.0000x reference)
//
#include <hip/hip_runtime.h>
#include <math.h>

#define NNODES 512   // 8*8*8
#define CIN 8
#define COUT 8
#define RR 8

// One block per (b,t) item. Thread = node. x[bt] slab (8 ch * 512 nodes = 16KB)
// staged in LDS; stencil + random-gather reads come from LDS; weights are
// wave-uniform -> scalar loads through the constant cache.
__global__ __launch_bounds__(512) void hybrid3d_kernel(
    const float* __restrict__ x,
    const float* __restrict__ conv_w,   // (8,8,3,3,3)
    const float* __restrict__ conv_b,   // (8,)
    const float* __restrict__ mix_w,    // (8,8,8)
    const float* __restrict__ mix_b,    // (8,)
    const float* __restrict__ alpha_p,  // (1,)
    const int*   __restrict__ rand_idx, // (512,8)
    float* __restrict__ out)
{
    __shared__ float xs[CIN * NNODES];

    const int bt  = blockIdx.x;
    const int tid = threadIdx.x;

    // ---- stage x[bt] (4096 floats) into LDS, vectorized ----
    {
        const float4* src = (const float4*)(x + (size_t)bt * (CIN * NNODES));
        float4* dst = (float4*)xs;
        dst[tid]       = src[tid];
        dst[tid + 512] = src[tid + 512];
    }
    __syncthreads();

    const int n = tid;
    const int d = n >> 6;
    const int h = (n >> 3) & 7;
    const int w = n & 7;

    // ---- gather indices for this node (contiguous 32B, coalesced) ----
    int idx[RR];
    {
        const int4* ip = (const int4*)(rand_idx + n * RR);
        int4 a0 = ip[0], a1 = ip[1];
        idx[0]=a0.x; idx[1]=a0.y; idx[2]=a0.z; idx[3]=a0.w;
        idx[4]=a1.x; idx[5]=a1.y; idx[6]=a1.z; idx[7]=a1.w;
    }

    const float alpha = alpha_p[0];
    const float a = 1.0f / (1.0f + __expf(-alpha));
    const float oma = 1.0f - a;

    // accumulators for all 8 output channels
    float accL[COUT], accR[COUT];
#pragma unroll
    for (int o = 0; o < COUT; ++o) {
        accL[o] = conv_b[o];
        accR[o] = mix_b[o];
    }

    // stencil tap offsets within the 27-element (3,3,3) kernel
    // order: center, d-1, d+1, h-1, h+1, w-1, w+1 (cross-correlation, SAME pad)
    // (kd,kh,kw) -> kd*9+kh*3+kw : (1,1,1)=13 (0,1,1)=4 (2,1,1)=22
    //                              (1,0,1)=10 (1,2,1)=16 (1,1,0)=12 (1,1,2)=14

    // process channels in two halves of 4 to bound register pressure
#pragma unroll
    for (int ch = 0; ch < 2; ++ch) {
        float v[4][7];
        float g[4][RR];
#pragma unroll
        for (int cc = 0; cc < 4; ++cc) {
            const int c = ch * 4 + cc;
            const float* xc = xs + c * NNODES;
            v[cc][0] = xc[n];
            v[cc][1] = (d > 0) ? xc[n - 64] : 0.0f;
            v[cc][2] = (d < 7) ? xc[n + 64] : 0.0f;
            v[cc][3] = (h > 0) ? xc[n - 8]  : 0.0f;
            v[cc][4] = (h < 7) ? xc[n + 8]  : 0.0f;
            v[cc][5] = (w > 0) ? xc[n - 1]  : 0.0f;
            v[cc][6] = (w < 7) ? xc[n + 1]  : 0.0f;
#pragma unroll
            for (int r = 0; r < RR; ++r)
                g[cc][r] = xc[idx[r]];
        }
#pragma unroll
        for (int o = 0; o < COUT; ++o) {
#pragma unroll
            for (int cc = 0; cc < 4; ++cc) {
                const int c = ch * 4 + cc;
                const float* wc = conv_w + (o * CIN + c) * 27;
                float aL = accL[o];
                aL = fmaf(wc[13], v[cc][0], aL);
                aL = fmaf(wc[ 4], v[cc][1], aL);
                aL = fmaf(wc[22], v[cc][2], aL);
                aL = fmaf(wc[10], v[cc][3], aL);
                aL = fmaf(wc[16], v[cc][4], aL);
                aL = fmaf(wc[12], v[cc][5], aL);
                aL = fmaf(wc[14], v[cc][6], aL);
                accL[o] = aL;
                const float* mc = mix_w + (o * CIN + c) * RR;
                float aR = accR[o];
#pragma unroll
                for (int r = 0; r < RR; ++r)
                    aR = fmaf(mc[r], g[cc][r], aR);
                accR[o] = aR;
            }
        }
    }

    // ---- blend + store (per-o stores are fully coalesced across the wave) ----
    float* outp = out + (size_t)bt * (COUT * NNODES);
#pragma unroll
    for (int o = 0; o < COUT; ++o)
        outp[o * NNODES + n] = a * accL[o] + oma * accR[o];
}

extern "C" void kernel_launch(void* const* d_in, const int* in_sizes, int n_in,
                              void* d_out, int out_size, void* d_ws, size_t ws_size,
                              hipStream_t stream) {
    const float* x       = (const float*)d_in[0];
    const float* conv_w  = (const float*)d_in[1];
    const float* conv_b  = (const float*)d_in[2];
    const float* mix_w   = (const float*)d_in[3];
    const float* mix_b   = (const float*)d_in[4];
    const float* alpha_p = (const float*)d_in[5];
    const int*   rand_i  = (const int*)d_in[6];
    float* out = (float*)d_out;

    const int BT = in_sizes[0] / (CIN * NNODES);   // 2048
    hybrid3d_kernel<<<BT, 512, 0, stream>>>(x, conv_w, conv_b, mix_w, mix_b,
                                            alpha_p, rand_i, out);
}

// Round 2
// 194.804 us; speedup vs baseline: 1.0003x; 1.0003x over previous
//
#include <hip/hip_runtime.h>
#include <math.h>

#define NNODES 512   // 8*8*8
#define CIN 8
#define COUT 8
#define RR 8
#define BTB 8                 // bt items per block
#define SLAB 4100             // 4096 floats + 4 pad words (16B-aligned, bank stride 4 per slab)
#define LDS_FLOATS (BTB * SLAB)
#define LDS_BYTES (LDS_FLOATS * 4 + NNODES * RR * 4)   // x slabs + staged indices

// ---- pre-kernel: fold sigmoid(alpha) into weights & bias --------------------
// ws layout: [0..959]  wsc[o][c][15]  (taps 0..6 = a*conv stencil taps, 7..14 = (1-a)*mix_w[r])
//            [960..967] bias2[o] = a*conv_b[o] + (1-a)*mix_b[o]
__global__ void prep_weights(const float* __restrict__ conv_w,
                             const float* __restrict__ conv_b,
                             const float* __restrict__ mix_w,
                             const float* __restrict__ mix_b,
                             const float* __restrict__ alpha_p,
                             float* __restrict__ ws) {
    const int t = threadIdx.x;
    const float alpha = alpha_p[0];
    const float a = 1.0f / (1.0f + expf(-alpha));
    if (t < 960) {
        const int oc = t / 15;     // o*8+c
        const int tap = t % 15;
        float v;
        if (tap < 7) {
            // stencil taps within 27-elem (3,3,3): center,(d-1),(d+1),(h-1),(h+1),(w-1),(w+1)
            const int off[7] = {13, 4, 22, 10, 16, 12, 14};
            v = a * conv_w[oc * 27 + off[tap]];
        } else {
            v = (1.0f - a) * mix_w[oc * RR + (tap - 7)];
        }
        ws[t] = v;
    } else if (t < 968) {
        const int o = t - 960;
        ws[960 + o] = a * conv_b[o] + (1.0f - a) * mix_b[o];
    }
}

// ---- main kernel: block = 8 bt items, wave = 8 bt x 8 nodes -----------------
extern "C" __global__ __launch_bounds__(512, 2) void hybrid3d_b8(
    const float* __restrict__ x,
    const int*   __restrict__ rand_idx,  // (512,8)
    const float* __restrict__ wsb,       // prep output: 960 weights + 8 bias
    float* __restrict__ out)
{
    extern __shared__ float xs[];                 // BTB slabs of SLAB floats
    int* idxs = (int*)(xs + LDS_FLOATS);          // 4096 staged indices

    const int blk = blockIdx.x;
    const int tid = threadIdx.x;

    // ---- stage x for 8 bt items (128 KB), float4, coalesced ----
    {
        const float4* src = (const float4*)(x + (size_t)blk * (BTB * CIN * NNODES));
#pragma unroll
        for (int f = 0; f < 16; ++f) {
            const int fi = f * 512 + tid;         // 0..8191 float4s
            const int s  = fi >> 10;              // slab
            const int w4 = fi & 1023;             // float4 within slab
            *((float4*)(xs + s * SLAB) + w4) = src[fi];
        }
        // stage indices (4096 ints = 1024 int4)
        const int4* isrc = (const int4*)rand_idx;
        int4* idst = (int4*)idxs;
        idst[tid]       = isrc[tid];
        idst[tid + 512] = isrc[tid + 512];
    }

    // bias to registers (wave-uniform -> s_load)
    float bias[COUT];
#pragma unroll
    for (int o = 0; o < COUT; ++o) bias[o] = wsb[960 + o];

    __syncthreads();

    const int lane = tid & 63;
    const int wv   = tid >> 6;       // 0..7  (= h coordinate)
    const int b8   = lane >> 3;      // bt within block
    const int n8   = lane & 7;       // = w coordinate
    const float* slab = xs + b8 * SLAB;
    float* outb = out + ((size_t)blk * BTB + b8) * (COUT * NNODES);

    for (int i = 0; i < 8; ++i) {    // i = d coordinate (uniform)
        const int n = i * 64 + wv * 8 + n8;

        // gather indices: LDS broadcast (8 lanes share each address)
        int idx[RR];
        {
            const int4* ip = (const int4*)(idxs + n * RR);
            int4 a0 = ip[0], a1 = ip[1];
            idx[0] = a0.x; idx[1] = a0.y; idx[2] = a0.z; idx[3] = a0.w;
            idx[4] = a1.x; idx[5] = a1.y; idx[6] = a1.z; idx[7] = a1.w;
        }

        float acc[COUT];
#pragma unroll
        for (int o = 0; o < COUT; ++o) acc[o] = bias[o];

#pragma unroll
        for (int c = 0; c < CIN; ++c) {
            const float* xc = slab + c * NNODES;
            // stencil values: d (uniform cond), h (wave-uniform), w (lane cond)
            const float v0 = xc[n];
            const float v1 = (i  > 0) ? xc[n - 64] : 0.0f;
            const float v2 = (i  < 7) ? xc[n + 64] : 0.0f;
            const float v3 = (wv > 0) ? xc[n - 8]  : 0.0f;
            const float v4 = (wv < 7) ? xc[n + 8]  : 0.0f;
            const float v5 = (n8 > 0) ? xc[n - 1]  : 0.0f;
            const float v6 = (n8 < 7) ? xc[n + 1]  : 0.0f;
            // gathered values: bank-spread via slab padding
            float g[RR];
#pragma unroll
            for (int r = 0; r < RR; ++r) g[r] = xc[idx[r]];

#pragma unroll
            for (int o = 0; o < COUT; ++o) {
                const float* wp = wsb + (o * CIN + c) * 15;   // uniform -> s_load
                float t = acc[o];
                t = fmaf(wp[0],  v0, t);
                t = fmaf(wp[1],  v1, t);
                t = fmaf(wp[2],  v2, t);
                t = fmaf(wp[3],  v3, t);
                t = fmaf(wp[4],  v4, t);
                t = fmaf(wp[5],  v5, t);
                t = fmaf(wp[6],  v6, t);
                t = fmaf(wp[7],  g[0], t);
                t = fmaf(wp[8],  g[1], t);
                t = fmaf(wp[9],  g[2], t);
                t = fmaf(wp[10], g[3], t);
                t = fmaf(wp[11], g[4], t);
                t = fmaf(wp[12], g[5], t);
                t = fmaf(wp[13], g[6], t);
                t = fmaf(wp[14], g[7], t);
                acc[o] = t;
            }
        }

#pragma unroll
        for (int o = 0; o < COUT; ++o)
            outb[o * NNODES + n] = acc[o];
    }
}

extern "C" void kernel_launch(void* const* d_in, const int* in_sizes, int n_in,
                              void* d_out, int out_size, void* d_ws, size_t ws_size,
                              hipStream_t stream) {
    const float* x       = (const float*)d_in[0];
    const float* conv_w  = (const float*)d_in[1];
    const float* conv_b  = (const float*)d_in[2];
    const float* mix_w   = (const float*)d_in[3];
    const float* mix_b   = (const float*)d_in[4];
    const float* alpha_p = (const float*)d_in[5];
    const int*   rand_i  = (const int*)d_in[6];
    float* out = (float*)d_out;
    float* ws  = (float*)d_ws;

    const int BT = in_sizes[0] / (CIN * NNODES);   // 2048

    prep_weights<<<1, 1024, 0, stream>>>(conv_w, conv_b, mix_w, mix_b, alpha_p, ws);

    static bool attr_set = false;   // idempotent opt-in for >64KB dynamic LDS (host-side, capture-safe)
    hipFuncSetAttribute((const void*)hybrid3d_b8,
                        hipFuncAttributeMaxDynamicSharedMemorySize, LDS_BYTES);
    (void)attr_set;

    hybrid3d_b8<<<BT / BTB, 512, LDS_BYTES, stream>>>(x, rand_i, ws, out);
}

// Round 3
// 116.632 us; speedup vs baseline: 1.6708x; 1.6702x over previous
//
#include <hip/hip_runtime.h>
#include <math.h>

#define NNODES 512
#define CIN 8
#define COUT 8
#define RR 8
#define BTB 4                      // bt items per block (1 per wave)
#define GUARD 64
#define CH_STRIDE 656              // halfwords: 64 guard + 512 data + 64 guard + 16 pad
#define SLAB_HW (CIN * CH_STRIDE)  // 5248 halfwords per bt
#define LDS_HW (BTB * SLAB_HW)     // 20992 halfwords = 41984 B

typedef __attribute__((ext_vector_type(8))) short short8;
typedef __attribute__((ext_vector_type(4))) float floatx4;

// ---- pre-kernel: fold sigmoid(alpha) into weights & bias --------------------
// ws layout: [0..959]  w[o][c][15] (taps 0..6 = a*conv stencil, 7..14 = (1-a)*mix_w)
//            [960..967] bias2[o] = a*conv_b[o] + (1-a)*mix_b[o]
__global__ void prep_weights(const float* __restrict__ conv_w,
                             const float* __restrict__ conv_b,
                             const float* __restrict__ mix_w,
                             const float* __restrict__ mix_b,
                             const float* __restrict__ alpha_p,
                             float* __restrict__ ws) {
    const int t = threadIdx.x;
    const float alpha = alpha_p[0];
    const float a = 1.0f / (1.0f + expf(-alpha));
    if (t < 960) {
        const int oc = t / 15;
        const int tap = t % 15;
        float v;
        if (tap < 7) {
            // (kd,kh,kw)->kd*9+kh*3+kw: center=13, d-=4, d+=22, h-=10, h+=16, w-=12, w+=14
            const int off[7] = {13, 4, 22, 10, 16, 12, 14};
            v = a * conv_w[oc * 27 + off[tap]];
        } else {
            v = (1.0f - a) * mix_w[oc * RR + (tap - 7)];
        }
        ws[t] = v;
    } else if (t < 968) {
        const int o = t - 960;
        ws[960 + o] = a * conv_b[o] + (1.0f - a) * mix_b[o];
    }
}

__device__ __forceinline__ unsigned int bf16_rne(float a) {
    unsigned int u = __float_as_uint(a);
    return (u + 0x7fffu + ((u >> 16) & 1u)) >> 16;
}
__device__ __forceinline__ unsigned int pack_bf16(float a, float b) {
    unsigned int ua = __float_as_uint(a);
    unsigned int ub = __float_as_uint(b);
    ua = (ua + 0x7fffu + ((ua >> 16) & 1u)) >> 16;
    ub = (ub + 0x7fffu + ((ub >> 16) & 1u)) & 0xffff0000u;
    return ua | ub;
}

// ---- main kernel: GEMM-ified. y[16n x 8o] tile = F[16n x 128k] @ W[128k x 8o]
// k = c*16 + tap; tap 0..6 stencil (c,d-,d+,h-,h+,w-,w+), 7..14 = g0..g7, 15 = 0.
// Wave = 1 bt; even lane-quads build taps 0..7, odd quads taps 8..15.
__global__ __launch_bounds__(256) void hybrid3d_mfma(
    const float* __restrict__ x,
    const int*   __restrict__ rand_idx,   // (512,8)
    const float* __restrict__ wsb,        // prep output
    float* __restrict__ out)
{
    __shared__ unsigned short lds16[LDS_HW];

    const int tid  = threadIdx.x;
    const int wave = tid >> 6;
    const int lane = tid & 63;
    const int quad = lane >> 4;
    const int r16  = lane & 15;
    const int oddh = quad & 1;
    const int c0   = quad >> 1;

    // ---- zero LDS (guards must be 0) ----
    {
        uint4* z = (uint4*)lds16;
#pragma unroll
        for (int i = 0; i < 11; ++i) {
            const int idx = tid + i * 256;
            if (idx < LDS_HW / 8) z[idx] = make_uint4(0u, 0u, 0u, 0u);
        }
    }

    // ---- B-fragments (weights) + bias: built once, live in VGPRs ----
    short8 bfrag[4];
#pragma unroll
    for (int ch = 0; ch < 4; ++ch) {
        union { unsigned int u[4]; short8 s; } bf;
#pragma unroll
        for (int jp = 0; jp < 4; ++jp) {
            const int gk = ch * 32 + quad * 8 + 2 * jp;   // even
            const int c  = gk >> 4;
            const int tap = gk & 15;
            float f0 = (r16 < 8 && tap < 15)     ? wsb[(r16 * CIN + c) * 15 + tap]     : 0.0f;
            float f1 = (r16 < 8 && tap + 1 < 15) ? wsb[(r16 * CIN + c) * 15 + tap + 1] : 0.0f;
            bf.u[jp] = pack_bf16(f0, f1);
        }
        bfrag[ch] = bf.s;
    }
    const float bias = (r16 < 8) ? wsb[960 + r16] : 0.0f;

    __syncthreads();

    // ---- stage x -> bf16 LDS slabs with guard rows ----
    {
        const float* xg = x + (size_t)blockIdx.x * (BTB * CIN * NNODES);
#pragma unroll
        for (int k = 0; k < 8; ++k) {
            const int q    = tid + k * 256;       // 0..2047 chunks of 8 floats
            const int bt_l = q >> 9;
            const int rem  = q & 511;
            const int c    = rem >> 6;
            const int m0   = (rem & 63) << 3;
            const float4* src = (const float4*)(xg + bt_l * (CIN * NNODES) + c * NNODES + m0);
            float4 f0 = src[0], f1 = src[1];
            uint4 pk;
            pk.x = pack_bf16(f0.x, f0.y);
            pk.y = pack_bf16(f0.z, f0.w);
            pk.z = pack_bf16(f1.x, f1.y);
            pk.w = pack_bf16(f1.z, f1.w);
            *((uint4*)&lds16[bt_l * SLAB_HW + c * CH_STRIDE + GUARD + m0]) = pk;
        }
    }
    __syncthreads();

    const int db = wave * SLAB_HW + c0 * CH_STRIDE + GUARD;  // data base (halfwords) for this lane's chunk-0 channel
    float* outb = out + ((size_t)blockIdx.x * BTB + wave) * (COUT * NNODES);

    for (int t = 0; t < 32; ++t) {
        const int m = t * 16 + r16;
        const int h = (m >> 3) & 7;
        const int w = m & 7;

        // gather indices for node m (L1-resident global, vmcnt domain)
        const int4* ip = (const int4*)(rand_idx + m * RR);
        const int4 i0 = ip[0];
        const int4 i1 = ip[1];

        const int sb = db + m;
        int va[8];
        va[0] = oddh ? (db + i0.y) : sb;        // even: center   | odd: g1
        va[1] = oddh ? (db + i0.z) : sb - 64;   // even: d-       | odd: g2
        va[2] = oddh ? (db + i0.w) : sb + 64;   // even: d+       | odd: g3
        va[3] = oddh ? (db + i1.x) : sb - 8;    // even: h-       | odd: g4
        va[4] = oddh ? (db + i1.y) : sb + 8;    // even: h+       | odd: g5
        va[5] = oddh ? (db + i1.z) : sb - 1;    // even: w-       | odd: g6
        va[6] = oddh ? (db + i1.w) : sb + 1;    // even: w+       | odd: g7
        va[7] = oddh ? sb          : (db + i0.x); // even: g0     | odd: pad (zeroed)

        const bool ok3 = oddh || (h > 0);
        const bool ok4 = oddh || (h < 7);
        const bool ok5 = oddh || (w > 0);
        const bool ok6 = oddh || (w < 7);
        const bool ok7 = !oddh;

        floatx4 acc = {bias, bias, bias, bias};

#pragma unroll
        for (int ch = 0; ch < 4; ++ch) {
            const int off = ch * 2 * CH_STRIDE;   // +2 channels per chunk (compile-time imm)
            unsigned int v0 = lds16[va[0] + off];
            unsigned int v1 = lds16[va[1] + off];
            unsigned int v2 = lds16[va[2] + off];
            unsigned int v3 = lds16[va[3] + off];
            unsigned int v4 = lds16[va[4] + off];
            unsigned int v5 = lds16[va[5] + off];
            unsigned int v6 = lds16[va[6] + off];
            unsigned int v7 = lds16[va[7] + off];
            v3 = ok3 ? v3 : 0u;
            v4 = ok4 ? v4 : 0u;
            v5 = ok5 ? v5 : 0u;
            v6 = ok6 ? v6 : 0u;
            v7 = ok7 ? v7 : 0u;
            union { unsigned int u[4]; short8 s; } af;
            af.u[0] = v0 | (v1 << 16);
            af.u[1] = v2 | (v3 << 16);
            af.u[2] = v4 | (v5 << 16);
            af.u[3] = v6 | (v7 << 16);
            acc = __builtin_amdgcn_mfma_f32_16x16x32_bf16(af.s, bfrag[ch], acc, 0, 0, 0);
        }

        // C/D layout: col=lane&15 (=o), row=quad*4+reg (=node within tile)
        if (r16 < 8) {
            float4* dst = (float4*)(outb + r16 * NNODES + t * 16 + quad * 4);
            *dst = *(float4*)&acc;
        }
    }
}

extern "C" void kernel_launch(void* const* d_in, const int* in_sizes, int n_in,
                              void* d_out, int out_size, void* d_ws, size_t ws_size,
                              hipStream_t stream) {
    const float* x       = (const float*)d_in[0];
    const float* conv_w  = (const float*)d_in[1];
    const float* conv_b  = (const float*)d_in[2];
    const float* mix_w   = (const float*)d_in[3];
    const float* mix_b   = (const float*)d_in[4];
    const float* alpha_p = (const float*)d_in[5];
    const int*   rand_i  = (const int*)d_in[6];
    float* out = (float*)d_out;
    float* ws  = (float*)d_ws;

    const int BT = in_sizes[0] / (CIN * NNODES);   // 2048

    prep_weights<<<1, 1024, 0, stream>>>(conv_w, conv_b, mix_w, mix_b, alpha_p, ws);
    hybrid3d_mfma<<<BT / BTB, 256, 0, stream>>>(x, rand_i, ws, out);
}

// Round 4
// 110.209 us; speedup vs baseline: 1.7682x; 1.0583x over previous
//
#include <hip/hip_runtime.h>
#include <math.h>

#define NNODES 512
#define CIN 8
#define COUT 8
#define RR 8
#define BTB 4                          // bt items per block (1 per wave)
#define GUARD 64                       // zeroed guard node-slots each side
#define SLOTS (GUARD + NNODES + GUARD) // 640 node slots per bt
#define SLAB_HW (SLOTS * 8)            // 5120 halfwords per bt (16 B per node)
#define LDS_HW (BTB * SLAB_HW)         // 20480 hw = 40960 B
#define WTAB 1024                      // float offset of addr table in ws

typedef __attribute__((ext_vector_type(8))) short short8;
typedef __attribute__((ext_vector_type(4))) float floatx4;

__device__ __forceinline__ unsigned int pack_bf16(float a, float b) {
    unsigned int ua = __float_as_uint(a);
    unsigned int ub = __float_as_uint(b);
    ua = (ua + 0x7fffu + ((ua >> 16) & 1u)) >> 16;
    ub = (ub + 0x7fffu + ((ub >> 16) & 1u)) & 0xffff0000u;
    return ua | ub;
}

// ---- prep: fold sigmoid(alpha) into weights/bias + build per-(t,lane) LDS
//      byte-offset table for all 4 MFMA taps.
// ws floats [0..959]:  w[o][c][15] (0..6 = a*stencil taps, 7..14 = (1-a)*mix_w)
//          [960..967]: bias2[o]
// ws ints  [1024 .. 1024+8192): int4 table[t*64+lane] = LDS byte offsets (i=0..3)
// k mapping: K = tap*8 + c. MFMA i covers taps {4i..4i+3}; quad q holds tap 4i+q.
// taps: 0 center, 1 d-, 2 d+, 3 h-, 4 h+, 5 w-, 6 w+, 7..14 g0..g7, 15 zero.
__global__ void prep(const float* __restrict__ conv_w,
                     const float* __restrict__ conv_b,
                     const float* __restrict__ mix_w,
                     const float* __restrict__ mix_b,
                     const float* __restrict__ alpha_p,
                     const int*   __restrict__ rand_idx,
                     float* __restrict__ ws) {
    const int t = threadIdx.x;
    const float a = 1.0f / (1.0f + expf(-alpha_p[0]));
    if (t < 960) {
        const int oc = t / 15;
        const int tap = t % 15;
        float v;
        if (tap < 7) {
            // (kd,kh,kw)->kd*9+kh*3+kw: center=13, d-=4, d+=22, h-=10, h+=16, w-=12, w+=14
            const int off[7] = {13, 4, 22, 10, 16, 12, 14};
            v = a * conv_w[oc * 27 + off[tap]];
        } else {
            v = (1.0f - a) * mix_w[oc * RR + (tap - 7)];
        }
        ws[t] = v;
    } else if (t < 968) {
        const int o = t - 960;
        ws[960 + o] = a * conv_b[o] + (1.0f - a) * mix_b[o];
    }

    int4* tab = (int4*)((int*)ws + WTAB);
    for (int e = t; e < 2048; e += 1024) {
        const int tt = e >> 6, lane = e & 63;
        const int q = lane >> 4, r16 = lane & 15;
        const int m = tt * 16 + r16;
        const int h = (m >> 3) & 7, w = m & 7;
        int off[4];
#pragma unroll
        for (int i = 0; i < 4; ++i) {
            const int tap = 4 * i + q;
            int o;
            if (tap == 0)       o = GUARD + m;
            else if (tap == 1)  o = GUARD + m - 64;                    // d- (guard-zero ok)
            else if (tap == 2)  o = GUARD + m + 64;                    // d+
            else if (tap == 3)  o = (h > 0) ? (GUARD + m - 8) : 0;     // h-
            else if (tap == 4)  o = (h < 7) ? (GUARD + m + 8) : 0;     // h+
            else if (tap == 5)  o = (w > 0) ? (GUARD + m - 1) : 0;     // w-
            else if (tap == 6)  o = (w < 7) ? (GUARD + m + 1) : 0;     // w+
            else if (tap <= 14) o = GUARD + rand_idx[m * RR + (tap - 7)];
            else                o = 0;                                 // tap15: zero slot
            off[i] = o * 16;   // bytes: 16 B per node slot
        }
        tab[e] = make_int4(off[0], off[1], off[2], off[3]);
    }
}

// ---- main: node-major bf16 LDS slots (8ch x 16B), A-frag = 1 ds_read_b128.
__global__ __launch_bounds__(256) void hybrid3d_v2(
    const float* __restrict__ x,
    const float* __restrict__ wsb,
    float* __restrict__ out)
{
    __shared__ unsigned short lds16[LDS_HW];
    const int tid  = threadIdx.x;
    const int wave = tid >> 6;
    const int lane = tid & 63;
    const int quad = lane >> 4;
    const int r16  = lane & 15;

    // zero guard slots (4 bt x 128 slots x 16 B)
    {
        const uint4 z = make_uint4(0u, 0u, 0u, 0u);
        for (int g = tid; g < BTB * 2 * GUARD; g += 256) {
            const int b = g >> 7;
            const int s = g & 127;
            const int slot = (s < GUARD) ? s : (NNODES + s);   // 0..63 | 576..639
            *(uint4*)&lds16[b * SLAB_HW + slot * 8] = z;
        }
    }

    // B-fragments (weights) + bias, built once into VGPRs
    short8 bfrag[4];
#pragma unroll
    for (int i = 0; i < 4; ++i) {
        const int tap = 4 * i + quad;
        union { unsigned int u[4]; short8 s; } bf;
#pragma unroll
        for (int jp = 0; jp < 4; ++jp) {
            const int c0 = 2 * jp, c1 = 2 * jp + 1;
            float f0 = (r16 < 8 && tap < 15) ? wsb[(r16 * CIN + c0) * 15 + tap] : 0.0f;
            float f1 = (r16 < 8 && tap < 15) ? wsb[(r16 * CIN + c1) * 15 + tap] : 0.0f;
            bf.u[jp] = pack_bf16(f0, f1);
        }
        bfrag[i] = bf.s;
    }
    const float bias = (r16 < 8) ? wsb[960 + r16] : 0.0f;

    // stage x -> node-major bf16 slots (transpose c into the slot)
    const float* xg = x + ((size_t)blockIdx.x * BTB + wave) * (CIN * NNODES);
    unsigned short* slab = lds16 + wave * SLAB_HW;
#pragma unroll
    for (int j = 0; j < 8; ++j) {
        const int n = lane + 64 * j;
        float v[8];
#pragma unroll
        for (int c = 0; c < 8; ++c) v[c] = xg[c * NNODES + n];
        uint4 pk;
        pk.x = pack_bf16(v[0], v[1]);
        pk.y = pack_bf16(v[2], v[3]);
        pk.z = pack_bf16(v[4], v[5]);
        pk.w = pack_bf16(v[6], v[7]);
        *(uint4*)&slab[(GUARD + n) * 8] = pk;
    }
    __syncthreads();

    const char* slabp = (const char*)slab;
    const int4* tab = (const int4*)((const int*)wsb + WTAB);
    float* outb = out + ((size_t)blockIdx.x * BTB + wave) * (COUT * NNODES);

#pragma unroll 2
    for (int t = 0; t < 32; ++t) {
        const int4 off = tab[t * 64 + lane];          // coalesced, L2-resident
        union { uint4 u; short8 s; } r0, r1, r2, r3;  // 4x ds_read_b128
        r0.u = *(const uint4*)(slabp + off.x);
        r1.u = *(const uint4*)(slabp + off.y);
        r2.u = *(const uint4*)(slabp + off.z);
        r3.u = *(const uint4*)(slabp + off.w);

        floatx4 acc_a = {bias, bias, bias, bias};
        floatx4 acc_b = {0.0f, 0.0f, 0.0f, 0.0f};
        acc_a = __builtin_amdgcn_mfma_f32_16x16x32_bf16(r0.s, bfrag[0], acc_a, 0, 0, 0);
        acc_b = __builtin_amdgcn_mfma_f32_16x16x32_bf16(r2.s, bfrag[2], acc_b, 0, 0, 0);
        acc_a = __builtin_amdgcn_mfma_f32_16x16x32_bf16(r1.s, bfrag[1], acc_a, 0, 0, 0);
        acc_b = __builtin_amdgcn_mfma_f32_16x16x32_bf16(r3.s, bfrag[3], acc_b, 0, 0, 0);

        // C/D: col=lane&15 (=o), row=quad*4+reg (=node in 16-tile)
        if (r16 < 8) {
            float4 res;
            res.x = acc_a.x + acc_b.x;
            res.y = acc_a.y + acc_b.y;
            res.z = acc_a.z + acc_b.z;
            res.w = acc_a.w + acc_b.w;
            *(float4*)(outb + r16 * NNODES + t * 16 + quad * 4) = res;
        }
    }
}

extern "C" void kernel_launch(void* const* d_in, const int* in_sizes, int n_in,
                              void* d_out, int out_size, void* d_ws, size_t ws_size,
                              hipStream_t stream) {
    const float* x       = (const float*)d_in[0];
    const float* conv_w  = (const float*)d_in[1];
    const float* conv_b  = (const float*)d_in[2];
    const float* mix_w   = (const float*)d_in[3];
    const float* mix_b   = (const float*)d_in[4];
    const float* alpha_p = (const float*)d_in[5];
    const int*   rand_i  = (const int*)d_in[6];
    float* out = (float*)d_out;
    float* ws  = (float*)d_ws;

    const int BT = in_sizes[0] / (CIN * NNODES);   // 2048

    prep<<<1, 1024, 0, stream>>>(conv_w, conv_b, mix_w, mix_b, alpha_p, rand_i, ws);
    hybrid3d_v2<<<BT / BTB, 256, 0, stream>>>(x, ws, out);
}

// Round 5
// 104.973 us; speedup vs baseline: 1.8563x; 1.0499x over previous
//
#include <hip/hip_runtime.h>
#include <math.h>

#define NNODES 512
#define CIN 8
#define COUT 8
#define RR 8
#define BTB 2                          // bt items per block (2 waves per bt)
#define GUARD 64                       // zeroed guard node-slots each side
#define SLOTS (GUARD + NNODES + GUARD) // 640 node slots per bt
#define SLAB_HW (SLOTS * 8)            // 5120 halfwords per bt (16 B per node slot)
#define LDS_HW (BTB * SLAB_HW)         // 10240 hw = 20480 B -> 4+ blocks/CU
#define WTAB 1024                      // float offset of addr table in ws

typedef __attribute__((ext_vector_type(8))) short short8;
typedef __attribute__((ext_vector_type(4))) float floatx4;

__device__ __forceinline__ unsigned int pack_bf16(float a, float b) {
    unsigned int ua = __float_as_uint(a);
    unsigned int ub = __float_as_uint(b);
    ua = (ua + 0x7fffu + ((ua >> 16) & 1u)) >> 16;
    ub = (ub + 0x7fffu + ((ub >> 16) & 1u)) & 0xffff0000u;
    return ua | ub;
}

// ---- prep: fold sigmoid(alpha) into weights/bias + per-(t,lane) LDS byte-offset table.
// ws floats [0..959]:  w[o][c][15] (0..6 = a*stencil taps, 7..14 = (1-a)*mix_w)
//          [960..967]: bias2[o]
// ws ints  [1024..1024+8192): int4 table[t*64+lane] = LDS byte offsets for MFMA i=0..3
// K = tap*8 + c. MFMA i covers taps {4i..4i+3}; quad q holds tap 4i+q.
// taps: 0 center, 1 d-, 2 d+, 3 h-, 4 h+, 5 w-, 6 w+, 7..14 g0..g7, 15 zero.
__global__ void prep(const float* __restrict__ conv_w,
                     const float* __restrict__ conv_b,
                     const float* __restrict__ mix_w,
                     const float* __restrict__ mix_b,
                     const float* __restrict__ alpha_p,
                     const int*   __restrict__ rand_idx,
                     float* __restrict__ ws) {
    const int t = threadIdx.x;
    const float a = 1.0f / (1.0f + expf(-alpha_p[0]));
    if (t < 960) {
        const int oc = t / 15;
        const int tap = t % 15;
        float v;
        if (tap < 7) {
            // (kd,kh,kw)->kd*9+kh*3+kw: center=13, d-=4, d+=22, h-=10, h+=16, w-=12, w+=14
            const int off[7] = {13, 4, 22, 10, 16, 12, 14};
            v = a * conv_w[oc * 27 + off[tap]];
        } else {
            v = (1.0f - a) * mix_w[oc * RR + (tap - 7)];
        }
        ws[t] = v;
    } else if (t < 968) {
        const int o = t - 960;
        ws[960 + o] = a * conv_b[o] + (1.0f - a) * mix_b[o];
    }

    int4* tab = (int4*)((int*)ws + WTAB);
    for (int e = t; e < 2048; e += 1024) {
        const int tt = e >> 6, lane = e & 63;
        const int q = lane >> 4, r16 = lane & 15;
        const int m = tt * 16 + r16;
        const int h = (m >> 3) & 7, w = m & 7;
        int off[4];
#pragma unroll
        for (int i = 0; i < 4; ++i) {
            const int tap = 4 * i + q;
            int o;
            if (tap == 0)       o = GUARD + m;
            else if (tap == 1)  o = GUARD + m - 64;                    // d- (guard zero)
            else if (tap == 2)  o = GUARD + m + 64;                    // d+
            else if (tap == 3)  o = (h > 0) ? (GUARD + m - 8) : 0;     // h-
            else if (tap == 4)  o = (h < 7) ? (GUARD + m + 8) : 0;     // h+
            else if (tap == 5)  o = (w > 0) ? (GUARD + m - 1) : 0;     // w-
            else if (tap == 6)  o = (w < 7) ? (GUARD + m + 1) : 0;     // w+
            else if (tap <= 14) o = GUARD + rand_idx[m * RR + (tap - 7)];
            else                o = 0;                                 // tap15 -> zero slot
            off[i] = o * 16;   // bytes (16 B per node slot)
        }
        tab[e] = make_int4(off[0], off[1], off[2], off[3]);
    }
}

// ---- main: node-major bf16 LDS slots, A-frag = 1 ds_read_b128, 2 waves per bt.
__global__ __launch_bounds__(256) void hybrid3d_v3(
    const float* __restrict__ x,
    const float* __restrict__ wsb,
    float* __restrict__ out)
{
    __shared__ unsigned short lds16[LDS_HW];
    const int tid  = threadIdx.x;
    const int wave = tid >> 6;
    const int lane = tid & 63;
    const int quad = lane >> 4;
    const int r16  = lane & 15;
    const int btl  = wave >> 1;     // bt within block (0..1)
    const int half = wave & 1;      // node-half handled by this wave

    // zero guard slots: 2 bt x 128 slots x 16 B -> exactly one uint4 per thread
    {
        const int b = tid >> 7;
        const int s = tid & 127;
        const int slot = (s < GUARD) ? s : (NNODES + s);   // 0..63 | 576..639
        *(uint4*)&lds16[b * SLAB_HW + slot * 8] = make_uint4(0u, 0u, 0u, 0u);
    }

    // B-fragments (weights) + bias, built once into VGPRs
    short8 bfrag[4];
#pragma unroll
    for (int i = 0; i < 4; ++i) {
        const int tap = 4 * i + quad;
        union { unsigned int u[4]; short8 s; } bf;
#pragma unroll
        for (int jp = 0; jp < 4; ++jp) {
            const int c0 = 2 * jp, c1 = 2 * jp + 1;
            float f0 = (r16 < 8 && tap < 15) ? wsb[(r16 * CIN + c0) * 15 + tap] : 0.0f;
            float f1 = (r16 < 8 && tap < 15) ? wsb[(r16 * CIN + c1) * 15 + tap] : 0.0f;
            bf.u[jp] = pack_bf16(f0, f1);
        }
        bfrag[i] = bf.s;
    }
    const float bias = (r16 < 8) ? wsb[960 + r16] : 0.0f;

    // stage x -> node-major bf16 slots (each wave stages its half of its bt)
    const float* xg = x + ((size_t)blockIdx.x * BTB + btl) * (CIN * NNODES);
    unsigned short* slab = lds16 + btl * SLAB_HW;
#pragma unroll
    for (int j = 0; j < 4; ++j) {
        const int n = half * 256 + j * 64 + lane;
        float v[8];
#pragma unroll
        for (int c = 0; c < 8; ++c) v[c] = xg[c * NNODES + n];
        uint4 pk;
        pk.x = pack_bf16(v[0], v[1]);
        pk.y = pack_bf16(v[2], v[3]);
        pk.z = pack_bf16(v[4], v[5]);
        pk.w = pack_bf16(v[6], v[7]);
        *(uint4*)&slab[(GUARD + n) * 8] = pk;
    }
    __syncthreads();

    const char* slabp = (const char*)slab;
    const int4* tab = (const int4*)((const int*)wsb + WTAB);
    float* outb = out + ((size_t)blockIdx.x * BTB + btl) * (COUT * NNODES);

#pragma unroll 2
    for (int tt = 0; tt < 16; ++tt) {
        const int t = half * 16 + tt;
        const int4 off = tab[t * 64 + lane];          // coalesced, L1/L2-resident
        union { uint4 u; short8 s; } r0, r1, r2, r3;  // 4x ds_read_b128
        r0.u = *(const uint4*)(slabp + off.x);
        r1.u = *(const uint4*)(slabp + off.y);
        r2.u = *(const uint4*)(slabp + off.z);
        r3.u = *(const uint4*)(slabp + off.w);

        floatx4 acc_a = {bias, bias, bias, bias};
        floatx4 acc_b = {0.0f, 0.0f, 0.0f, 0.0f};
        acc_a = __builtin_amdgcn_mfma_f32_16x16x32_bf16(r0.s, bfrag[0], acc_a, 0, 0, 0);
        acc_b = __builtin_amdgcn_mfma_f32_16x16x32_bf16(r2.s, bfrag[2], acc_b, 0, 0, 0);
        acc_a = __builtin_amdgcn_mfma_f32_16x16x32_bf16(r1.s, bfrag[1], acc_a, 0, 0, 0);
        acc_b = __builtin_amdgcn_mfma_f32_16x16x32_bf16(r3.s, bfrag[3], acc_b, 0, 0, 0);

        // C/D: col=lane&15 (=o), row=quad*4+reg (node within 16-tile)
        if (r16 < 8) {
            float4 res;
            res.x = acc_a.x + acc_b.x;
            res.y = acc_a.y + acc_b.y;
            res.z = acc_a.z + acc_b.z;
            res.w = acc_a.w + acc_b.w;
            *(float4*)(outb + r16 * NNODES + t * 16 + quad * 4) = res;
        }
    }
}

extern "C" void kernel_launch(void* const* d_in, const int* in_sizes, int n_in,
                              void* d_out, int out_size, void* d_ws, size_t ws_size,
                              hipStream_t stream) {
    const float* x       = (const float*)d_in[0];
    const float* conv_w  = (const float*)d_in[1];
    const float* conv_b  = (const float*)d_in[2];
    const float* mix_w   = (const float*)d_in[3];
    const float* mix_b   = (const float*)d_in[4];
    const float* alpha_p = (const float*)d_in[5];
    const int*   rand_i  = (const int*)d_in[6];
    float* out = (float*)d_out;
    float* ws  = (float*)d_ws;

    const int BT = in_sizes[0] / (CIN * NNODES);   // 2048

    prep<<<1, 1024, 0, stream>>>(conv_w, conv_b, mix_w, mix_b, alpha_p, rand_i, ws);
    hybrid3d_v3<<<BT / BTB, 256, 0, stream>>>(x, ws, out);
}